// Round 8
// baseline (259.847 us; speedup 1.0000x reference)
//
#include <hip/hip_runtime.h>
#include <math.h>

#define NB 2
#define NS 2048
#define ND 1024
#define NH 16
#define NDH 64
#define NM (NB * NS)   // 4096 rows total
#define K2 (2 * ND)    // 2048: split width [hi | lo]

typedef unsigned short ushortT;
typedef __attribute__((ext_vector_type(8))) short bf16x8;   // 8 bf16 = 4 VGPRs
typedef __attribute__((ext_vector_type(4))) float f32x4;
typedef __attribute__((ext_vector_type(16))) float f32x16;  // 32x32 accumulator

__device__ inline unsigned short f2bf(float f) {
    union { float f; unsigned u; } v; v.f = f;
    unsigned r = v.u + 0x7FFFu + ((v.u >> 16) & 1u);  // RNE
    return (unsigned short)(r >> 16);
}
__device__ inline float bf2f(unsigned short h) {
    union { unsigned u; float f; } v; v.u = ((unsigned)h) << 16; return v.f;
}
__device__ inline unsigned cvt_pk_bf16(float lo, float hi) {
    unsigned r;
    asm("v_cvt_pk_bf16_f32 %0, %1, %2" : "=v"(r) : "v"(lo), "v"(hi));
    return r;
}
__device__ inline void gl_lds16(const ushortT* g, ushortT* l) {
    __builtin_amdgcn_global_load_lds(
        (const __attribute__((address_space(1))) unsigned*)g,
        (__attribute__((address_space(3))) unsigned*)l, 16, 0, 0);
}

// 0.125 (1/sqrt(64)) * log2(e): softmax runs in exp2 domain
#define QSC 0.18033688011112042f

// ---------------------------------------------------------------------------
// split_x: x fp32 [NM x ND] -> x_hi bf16 [NM x ND]
// ---------------------------------------------------------------------------
__global__ __launch_bounds__(256) void split_x(
    const float* __restrict__ x, ushortT* __restrict__ xh)
{
    int idx = (blockIdx.x * 256 + threadIdx.x) * 4;
    float4 v = *(const float4*)&x[idx];
    float fv[4] = {v.x, v.y, v.z, v.w};
    union { ushortT s[4]; uint2 u; } o;
#pragma unroll
    for (int j = 0; j < 4; ++j) o.s[j] = f2bf(fv[j]);
    *(uint2*)&xh[idx] = o.u;
}

// ---------------------------------------------------------------------------
// split_w_t: W fp32 [K x N] -> transposed bf16.
// z<3: hi-only to WtH[z] ([ND x ND]); z==3: hi|lo to WtO ([ND x K2]).
// grid (16,16,4)
// ---------------------------------------------------------------------------
__global__ __launch_bounds__(256) void split_w_t(
    const float* __restrict__ Wq, const float* __restrict__ Wk,
    const float* __restrict__ Wv, const float* __restrict__ Wo,
    ushortT* __restrict__ WtH, ushortT* __restrict__ WtO)
{
    const int z = blockIdx.z;
    const float* __restrict__ W = (z == 0) ? Wq : (z == 1) ? Wk : (z == 2) ? Wv : Wo;

    const int k0 = blockIdx.y * 64, n0 = blockIdx.x * 64;
    const int t = threadIdx.x;
    __shared__ float Ls[64][65];

#pragma unroll
    for (int i = 0; i < 4; ++i) {
        int kl = i * 16 + (t >> 4);
        int nl = (t & 15) << 2;
        float4 w4 = *(const float4*)&W[(size_t)(k0 + kl) * ND + n0 + nl];
        Ls[nl + 0][kl] = w4.x;
        Ls[nl + 1][kl] = w4.y;
        Ls[nl + 2][kl] = w4.z;
        Ls[nl + 3][kl] = w4.w;
    }
    __syncthreads();
#pragma unroll
    for (int i = 0; i < 16; ++i) {
        int flat = i * 256 + t;
        int n = flat >> 6, kk = flat & 63;
        float val = Ls[n][kk];
        unsigned short hi = f2bf(val);
        if (z < 3) {
            WtH[(size_t)z * ND * ND + (size_t)(n0 + n) * ND + (k0 + kk)] = hi;
        } else {
            WtO[(size_t)(n0 + n) * K2 + (k0 + kk)]      = hi;
            WtO[(size_t)(n0 + n) * K2 + ND + (k0 + kk)] = f2bf(val - bf2f(hi));
        }
    }
}

// ---------------------------------------------------------------------------
// GEMM: 64x128 tile (M x N), BK=32, 4 waves (2x2, each 32x64), gl_lds16.
// 3-buffer counted-vmcnt pipeline (2 stages in flight, vmcnt(3) steady).
// Per-thread global row pointers hoisted; per-step offset is a scalar add.
// XCD panel-group swizzle: the 8 n-blocks sharing an A-panel -> one XCD.
// OUTMODE 0: C = x_hi @ WtH[z]^T + b  (K=1024) -> z==0: Q*QSC; z==1: K;
//            z==2: V transposed [B,H,DH,S].  grid (8, 64, 3).
// OUTMODE 1: C = A2 @ WtO^T + b (split hh+hl+lh, virtual K=3072) -> fp32,
//            grid (8, 64).
// ---------------------------------------------------------------------------
template <int OUTMODE>
__global__ __launch_bounds__(256) void gemm_split(
    const ushortT* __restrict__ A2,   // OUTMODE0: [NM x ND] ; OUTMODE1: [NM x K2]
    const ushortT* __restrict__ Wt,   // OUTMODE0: WtH base ; OUTMODE1: WtO
    const float* __restrict__ b0, const float* __restrict__ b1, const float* __restrict__ b2,
    ushortT* __restrict__ Qo, ushortT* __restrict__ Ko, ushortT* __restrict__ Vtg,
    float* __restrict__ Ofp)
{
    const int z = blockIdx.z;
    const int AS = OUTMODE ? K2 : ND;   // row stride of A and B
    const ushortT* __restrict__ Bt = OUTMODE ? Wt : Wt + (size_t)z * ND * ND;
    const float* __restrict__ bias = (z == 0) ? b0 : (z == 1) ? b1 : b2;

    // XCD panel-group swizzle, bijective on [0,512):
    // xcd = L%8 fixed per A-panel group (m ≡ rx mod 8), n sweeps inside.
    const int L = blockIdx.y * 8 + blockIdx.x;
    const int rx = L & 7, q = L >> 3;            // q in [0,64)
    const int m0 = (((q >> 3) << 3) + rx) * 64;  // m-tile in [0,64)
    const int n0 = (q & 7) * 128;                // n-tile in [0,8)

    const int tid = threadIdx.x;
    const int lane = tid & 63, w = tid >> 6;
    const int wrow = w >> 1, wcol = w & 1;       // wave -> 32x64 sub-tile
    const int a = lane & 15, g = lane >> 4;

    __shared__ __align__(16) ushortT Abuf[3][64 * 32];    // 3 x 4 KB
    __shared__ __align__(16) ushortT Bbuf[3][128 * 32];   // 3 x 8 KB

    f32x4 acc[2][4] = {};

    // ---- hoisted staging addresses (per-thread) ----
    const int rS  = tid >> 2;                       // 0..63
    const int scS = (tid & 3) ^ ((rS >> 1) & 3);    // source-side XOR swizzle
    const ushortT* pA  = A2 + (size_t)(m0 + rS) * AS + (scS << 3);
    const ushortT* pB0 = Bt + (size_t)(n0 + rS) * AS + (scS << 3);
    const ushortT* pB1 = pB0 + (size_t)64 * AS;     // rows 64..127, same swizzle
    const int dA  = tid * 8;
    const int dB0 = tid * 8;
    const int dB1 = 2048 + tid * 8;

    const int swz = (a >> 1) & 3;
    const int nst = OUTMODE ? 96 : 32;

    auto stage = [&](int bufi, int ks) {
        const int kp = ks * 32;
        const int ac = OUTMODE ? ((kp < ND) ? kp : kp - ND) : kp;          // A: [hi,hi,lo]
        const int bc = OUTMODE ? ((kp < 2 * ND) ? kp : kp - 2 * ND) : kp;  // B: [hi,lo,hi]
        gl_lds16(pA  + ac, &Abuf[bufi][dA]);
        gl_lds16(pB0 + bc, &Bbuf[bufi][dB0]);
        gl_lds16(pB1 + bc, &Bbuf[bufi][dB1]);
    };

    stage(0, 0);
    stage(1, 1);                       // 6 loads/wave outstanding
    int cur = 0;
    for (int i = 0; i < nst; ++i) {
        if (i + 1 < nst) {
            // stage(i) landed iff only stage(i+1)'s 3 loads remain
            asm volatile("s_waitcnt vmcnt(3)" ::: "memory");
        } else {
            asm volatile("s_waitcnt vmcnt(0)" ::: "memory");
        }
        __builtin_amdgcn_s_barrier();

        if (i + 2 < nst) {
            int nb = cur + 2; if (nb >= 3) nb -= 3;
            stage(nb, i + 2);          // overwrites buf[(i-1)%3]: safe post-barrier
        }

        bf16x8 af[2], bfr[4];
#pragma unroll
        for (int ii = 0; ii < 2; ++ii)
            af[ii] = *(const bf16x8*)&Abuf[cur][(wrow * 32 + ii * 16 + a) * 32 + ((g ^ swz) << 3)];
#pragma unroll
        for (int j = 0; j < 4; ++j)
            bfr[j] = *(const bf16x8*)&Bbuf[cur][(wcol * 64 + j * 16 + a) * 32 + ((g ^ swz) << 3)];
#pragma unroll
        for (int ii = 0; ii < 2; ++ii)
#pragma unroll
            for (int j = 0; j < 4; ++j)
                acc[ii][j] = __builtin_amdgcn_mfma_f32_16x16x32_bf16(af[ii], bfr[j], acc[ii][j], 0, 0, 0);

        ++cur; if (cur == 3) cur = 0;
    }

    float bj[4];
#pragma unroll
    for (int j = 0; j < 4; ++j) bj[j] = bias[n0 + wcol * 64 + j * 16 + a];

#pragma unroll
    for (int i = 0; i < 2; ++i) {
#pragma unroll
        for (int r = 0; r < 4; ++r) {
            int grow = m0 + wrow * 32 + i * 16 + g * 4 + r;
#pragma unroll
            for (int j = 0; j < 4; ++j) {
                int gcol = n0 + wcol * 64 + j * 16 + a;
                float v = acc[i][j][r] + bj[j];
                if (OUTMODE == 1) {
                    Ofp[(size_t)grow * ND + gcol] = v;
                } else {
                    int b = grow >> 11, s = grow & (NS - 1);
                    int h = gcol >> 6, dh = gcol & 63;
                    if (z == 0) {
                        Qo[((size_t)(b * NH + h) * NS + s) * NDH + dh] = f2bf(v * QSC);
                    } else if (z == 1) {
                        Ko[((size_t)(b * NH + h) * NS + s) * NDH + dh] = f2bf(v);
                    } else {
                        Vtg[((size_t)(b * NH + h) * NDH + dh) * NS + s] = f2bf(v);
                    }
                }
            }
        }
    }
}

// ---------------------------------------------------------------------------
// Flash attention, 32x32x16 MFMA, swapped QK^T (lane = q-row), in-register P.
// Q pre-scaled by 0.125*log2e -> softmax in exp2 domain (v_exp_f32 direct).
// cvt_pk_bf16 P-packing; defer-max rescale (THR=8 in log2 units).
// Block = 4 waves x 32 q-rows = 128 q. KV tile 64, double-buffered gl_lds.
// ---------------------------------------------------------------------------
__global__ __launch_bounds__(256) void attn_fwd2(
    const ushortT* __restrict__ Q, const ushortT* __restrict__ K,
    const ushortT* __restrict__ Vt, ushortT* __restrict__ A2o)
{
    const int bh = blockIdx.y;
    const int b = bh >> 4, h = bh & 15;
    const int q0 = blockIdx.x * 128;
    const int tid = threadIdx.x, lane = tid & 63, w = tid >> 6;
    const int ql = lane & 31;   // this lane's q (col of St / O^T)
    const int hi = lane >> 5;

    // 32 KB total: [K dbuf 16KB | V dbuf 16KB]; reused as epilogue scratch
    __shared__ __align__(16) unsigned smem4[8192];
    ushortT* sK = (ushortT*)smem4;          // [2][64*64]
    ushortT* sV = sK + 2 * 4096;            // [2][64*64]

    const ushortT* __restrict__ Kb  = K  + (size_t)bh * NS * NDH;   // [s][64]
    const ushortT* __restrict__ Vtb = Vt + (size_t)bh * NDH * NS;   // [d][S]

    // Q fragments (B-operand), already scaled: col=ql, k -> d = kc*16 + hi*8 + j
    bf16x8 qf[4];
    {
        const ushortT* qrow = Q + (size_t)bh * NS * NDH + (size_t)(q0 + w * 32 + ql) * NDH + hi * 8;
#pragma unroll
        for (int kc = 0; kc < 4; ++kc) qf[kc] = *(const bf16x8*)(qrow + kc * 16);
    }

    const int srw = lane >> 3;   // staging: row-in-group 0..7
    const int scc = lane & 7;    // staging: chunk 0..7

    float m_run = -INFINITY, l_run = 0.f;
    f32x16 oat[2] = {};

    // ---- stage tile 0 into buf 0 ----
#pragma unroll
    for (int c = 0; c < 2; ++c) {
        int rK = c * 32 + w * 8 + srw;
        gl_lds16(&Kb[(size_t)rK * NDH + ((scc ^ srw) << 3)], &sK[(c * 256 + w * 64) * 8]);
        gl_lds16(&Vtb[(size_t)rK * NS + ((scc ^ srw) << 3)], &sV[(c * 256 + w * 64) * 8]);
    }

    for (int t = 0; t < NS / 64; ++t) {
        const int cur = t & 1;
        __syncthreads();   // buf[cur] ready (loads are a full tile old); prev reads done
        if (t + 1 < NS / 64) {
            const int nxt = cur ^ 1;
            const int kv1 = (t + 1) * 64;
#pragma unroll
            for (int c = 0; c < 2; ++c) {
                int rK = c * 32 + w * 8 + srw;
                gl_lds16(&Kb[(size_t)(kv1 + rK) * NDH + ((scc ^ srw) << 3)],
                         &sK[(nxt * 4096) + (c * 256 + w * 64) * 8]);
                gl_lds16(&Vtb[(size_t)rK * NS + kv1 + ((scc ^ srw) << 3)],
                         &sV[(nxt * 4096) + (c * 256 + w * 64) * 8]);
            }
        }
        const ushortT* kbuf = sK + cur * 4096;
        const ushortT* vbuf = sV + cur * 4096;

        // ---- St[s] = K_sub @ Q^T : rows=kv, cols=q (exp2-domain scores) ----
        f32x16 st[2] = {};
#pragma unroll
        for (int s = 0; s < 2; ++s) {
            const int kv = s * 32 + ql;
#pragma unroll
            for (int kc = 0; kc < 4; ++kc) {
                bf16x8 kf = *(const bf16x8*)&kbuf[kv * 64 + (((kc * 2 + hi) ^ (ql & 7)) << 3)];
                st[s] = __builtin_amdgcn_mfma_f32_32x32x16_bf16(kf, qf[kc], st[s], 0, 0, 0);
            }
        }

        // ---- online softmax (exp2 domain); lane owns q = ql, pair lane^32 ----
        float mx = -INFINITY;
#pragma unroll
        for (int s = 0; s < 2; ++s)
#pragma unroll
            for (int r = 0; r < 16; ++r) mx = fmaxf(mx, st[s][r]);
        mx = fmaxf(mx, __shfl_xor(mx, 32));

        if (!__all(mx - m_run <= 8.0f)) {   // defer-max: P bounded by 2^8
            float mn = fmaxf(m_run, mx);
            float al = __builtin_amdgcn_exp2f(m_run - mn);
            m_run = mn;
            l_run *= al;
#pragma unroll
            for (int dt = 0; dt < 2; ++dt)
#pragma unroll
                for (int r = 0; r < 16; ++r) oat[dt][r] *= al;
        }
        float rs = 0.f;
#pragma unroll
        for (int s = 0; s < 2; ++s)
#pragma unroll
            for (int r = 0; r < 16; ++r) {
                float e = __builtin_amdgcn_exp2f(st[s][r] - m_run);
                st[s][r] = e;
                rs += e;
            }
        rs += __shfl_xor(rs, 32);
        l_run += rs;

        // ---- O^T += V^T @ P^T : per 16-kv step, P B-frag via cvt_pk + shfl ----
#pragma unroll
        for (int ts = 0; ts < 4; ++ts) {
            const int s = ts >> 1, rb = 8 * (ts & 1);
            unsigned u0 = cvt_pk_bf16(st[s][rb + 0], st[s][rb + 1]);
            unsigned u1 = cvt_pk_bf16(st[s][rb + 2], st[s][rb + 3]);
            unsigned v0 = cvt_pk_bf16(st[s][rb + 4], st[s][rb + 5]);
            unsigned v1 = cvt_pk_bf16(st[s][rb + 6], st[s][rb + 7]);
            unsigned t0 = hi ? u0 : v0;
            unsigned t1 = hi ? u1 : v1;
            unsigned t0s = __shfl_xor(t0, 32);
            unsigned t1s = __shfl_xor(t1, 32);
            union { unsigned u[4]; bf16x8 v; } pf;
            pf.u[0] = hi ? t0s : u0;
            pf.u[1] = hi ? t1s : u1;
            pf.u[2] = hi ? v0 : t0s;
            pf.u[3] = hi ? v1 : t1s;
#pragma unroll
            for (int dt = 0; dt < 2; ++dt) {
                bf16x8 vf = *(const bf16x8*)&vbuf[(dt * 32 + ql) * 64 + (((ts * 2 + hi) ^ (ql & 7)) << 3)];
                oat[dt] = __builtin_amdgcn_mfma_f32_32x32x16_bf16(vf, pf.v, oat[dt], 0, 0, 0);
            }
        }
    }

    // ---- epilogue: O^T -> LDS (xor-swizzled) -> split hi/lo gathered store ----
    __syncthreads();
    unsigned* osc = smem4 + w * 2048;   // per-wave [32 q][64 d]
    float inv = 1.0f / l_run;
#pragma unroll
    for (int dt = 0; dt < 2; ++dt)
#pragma unroll
        for (int r = 0; r < 16; ++r) {
            int d = dt * 32 + (r & 3) + 8 * (r >> 2) + 4 * hi;
            float o = oat[dt][r] * inv;
            unsigned short hb = f2bf(o);
            unsigned short lb = f2bf(o - bf2f(hb));
            osc[ql * 64 + (d ^ ql)] = (unsigned)hb | ((unsigned)lb << 16);
        }
    __syncthreads();
    const int qrd = lane >> 3;
    const int dbase = (lane & 7) * 8;
#pragma unroll
    for (int p = 0; p < 4; ++p) {
        int q = p * 8 + qrd;
        unsigned wv[8];
#pragma unroll
        for (int k = 0; k < 8; ++k)
            wv[k] = osc[q * 64 + ((dbase + k) ^ q)];
        union { ushortT s[8]; bf16x8 v; } hs, ls;
#pragma unroll
        for (int k = 0; k < 8; ++k) {
            hs.s[k] = (ushortT)(wv[k] & 0xffffu);
            ls.s[k] = (ushortT)(wv[k] >> 16);
        }
        size_t row = (size_t)(b * NS + q0 + w * 32 + q) * K2 + h * 64 + dbase;
        *(bf16x8*)&A2o[row]      = hs.v;
        *(bf16x8*)&A2o[row + ND] = ls.v;
    }
}

// ---------------------------------------------------------------------------
extern "C" void kernel_launch(void* const* d_in, const int* in_sizes, int n_in,
                              void* d_out, int out_size, void* d_ws, size_t ws_size,
                              hipStream_t stream)
{
    const float* x  = (const float*)d_in[0];
    const float* Wq = (const float*)d_in[1];
    const float* bq = (const float*)d_in[2];
    const float* Wk = (const float*)d_in[3];
    const float* bk = (const float*)d_in[4];
    const float* Wv = (const float*)d_in[5];
    const float* bv = (const float*)d_in[6];
    const float* Wo = (const float*)d_in[7];
    const float* bo = (const float*)d_in[8];
    float* out = (float*)d_out;

    // ws: xh 8.4 | WtH 6.3 | WtO 4.2 | Q 8.4 | K 8.4 | Vt 8.4 | A2 16.8 = 60.8 MB
    ushortT* xh  = (ushortT*)d_ws;
    ushortT* WtH = xh  + (size_t)NM * ND;
    ushortT* WtO = WtH + (size_t)3 * ND * ND;
    ushortT* Qb  = WtO + (size_t)ND * K2;
    ushortT* Kb  = Qb  + (size_t)NM * ND;
    ushortT* Vtg = Kb  + (size_t)NM * ND;
    ushortT* A2  = Vtg + (size_t)NM * ND;

    split_x<<<dim3(NM * ND / 1024), 256, 0, stream>>>(x, xh);
    split_w_t<<<dim3(16, 16, 4), 256, 0, stream>>>(Wq, Wk, Wv, Wo, WtH, WtO);
    gemm_split<0><<<dim3(8, 64, 3), 256, 0, stream>>>(
        xh, WtH, bq, bk, bv, Qb, Kb, Vtg, nullptr);
    attn_fwd2<<<dim3(NS / 128, NB * NH), 256, 0, stream>>>(Qb, Kb, Vtg, A2);
    gemm_split<1><<<dim3(8, 64), 256, 0, stream>>>(
        A2, WtO, bo, bo, bo, nullptr, nullptr, nullptr, out);
}

// Round 9
// 253.550 us; speedup vs baseline: 1.0248x; 1.0248x over previous
//
#include <hip/hip_runtime.h>
#include <math.h>

#define NB 2
#define NS 2048
#define ND 1024
#define NH 16
#define NDH 64
#define NM (NB * NS)   // 4096 rows total
#define K2 (2 * ND)    // 2048: split width [hi | lo]

typedef unsigned short ushortT;
typedef __attribute__((ext_vector_type(8))) short bf16x8;   // 8 bf16 = 4 VGPRs
typedef __attribute__((ext_vector_type(4))) float f32x4;
typedef __attribute__((ext_vector_type(16))) float f32x16;  // 32x32 accumulator

__device__ inline unsigned short f2bf(float f) {
    union { float f; unsigned u; } v; v.f = f;
    unsigned r = v.u + 0x7FFFu + ((v.u >> 16) & 1u);  // RNE
    return (unsigned short)(r >> 16);
}
__device__ inline float bf2f(unsigned short h) {
    union { unsigned u; float f; } v; v.u = ((unsigned)h) << 16; return v.f;
}
__device__ inline unsigned cvt_pk_bf16(float lo, float hi) {
    unsigned r;
    asm("v_cvt_pk_bf16_f32 %0, %1, %2" : "=v"(r) : "v"(lo), "v"(hi));
    return r;
}
__device__ inline void gl_lds16(const ushortT* g, ushortT* l) {
    __builtin_amdgcn_global_load_lds(
        (const __attribute__((address_space(1))) unsigned*)g,
        (__attribute__((address_space(3))) unsigned*)l, 16, 0, 0);
}

// 0.125 (1/sqrt(64)) * log2(e): softmax runs in exp2 domain
#define QSC 0.18033688011112042f

// ---------------------------------------------------------------------------
// split_x: x fp32 [NM x ND] -> x_hi bf16 [NM x ND]
// ---------------------------------------------------------------------------
__global__ __launch_bounds__(256) void split_x(
    const float* __restrict__ x, ushortT* __restrict__ xh)
{
    int idx = (blockIdx.x * 256 + threadIdx.x) * 4;
    float4 v = *(const float4*)&x[idx];
    float fv[4] = {v.x, v.y, v.z, v.w};
    union { ushortT s[4]; uint2 u; } o;
#pragma unroll
    for (int j = 0; j < 4; ++j) o.s[j] = f2bf(fv[j]);
    *(uint2*)&xh[idx] = o.u;
}

// ---------------------------------------------------------------------------
// split_w_t: W fp32 [K x N] -> transposed bf16.
// z<3: hi-only to WtH[z] ([ND x ND]); z==3: hi|lo to WtO ([ND x K2]).
// grid (16,16,4)
// ---------------------------------------------------------------------------
__global__ __launch_bounds__(256) void split_w_t(
    const float* __restrict__ Wq, const float* __restrict__ Wk,
    const float* __restrict__ Wv, const float* __restrict__ Wo,
    ushortT* __restrict__ WtH, ushortT* __restrict__ WtO)
{
    const int z = blockIdx.z;
    const float* __restrict__ W = (z == 0) ? Wq : (z == 1) ? Wk : (z == 2) ? Wv : Wo;

    const int k0 = blockIdx.y * 64, n0 = blockIdx.x * 64;
    const int t = threadIdx.x;
    __shared__ float Ls[64][65];

#pragma unroll
    for (int i = 0; i < 4; ++i) {
        int kl = i * 16 + (t >> 4);
        int nl = (t & 15) << 2;
        float4 w4 = *(const float4*)&W[(size_t)(k0 + kl) * ND + n0 + nl];
        Ls[nl + 0][kl] = w4.x;
        Ls[nl + 1][kl] = w4.y;
        Ls[nl + 2][kl] = w4.z;
        Ls[nl + 3][kl] = w4.w;
    }
    __syncthreads();
#pragma unroll
    for (int i = 0; i < 16; ++i) {
        int flat = i * 256 + t;
        int n = flat >> 6, kk = flat & 63;
        float val = Ls[n][kk];
        unsigned short hi = f2bf(val);
        if (z < 3) {
            WtH[(size_t)z * ND * ND + (size_t)(n0 + n) * ND + (k0 + kk)] = hi;
        } else {
            WtO[(size_t)(n0 + n) * K2 + (k0 + kk)]      = hi;
            WtO[(size_t)(n0 + n) * K2 + ND + (k0 + kk)] = f2bf(val - bf2f(hi));
        }
    }
}

// ---------------------------------------------------------------------------
// out_init: out[m][n] = bo[n]  (bias base for the atomic split-K out-proj)
// ---------------------------------------------------------------------------
__global__ __launch_bounds__(256) void out_init(
    const float* __restrict__ bo, float* __restrict__ out)
{
    int idx = blockIdx.x * 256 + threadIdx.x;   // NM*ND/4 threads
    int n4 = (idx & 255) << 2;
    int m = idx >> 8;
    float4 b4 = *(const float4*)&bo[n4];
    *(float4*)&out[(size_t)m * ND + n4] = b4;
}

// ---------------------------------------------------------------------------
// GEMM: 128x128 tile, BK=32, 4 waves (2x2 of 64x64), gl_lds16.
// 3-buffer counted-vmcnt pipeline (2 stages in flight, vmcnt(4) steady).
// XCD panel-group swizzle: 8 n-blocks sharing an A-panel -> one XCD.
// OUTMODE 0: C = x_hi @ WtH[z]^T + b (K=1024) -> z0: Q*QSC; z1: K; z2: V^T.
//            grid (8, 32, 3).
// OUTMODE 1: split-K halves of C = A2 @ WtO^T (virtual K=3072; z=half),
//            atomicAdd into bias-initialized fp32 out. grid (8, 32, 2).
// ---------------------------------------------------------------------------
template <int OUTMODE>
__global__ __launch_bounds__(256) void gemm_split(
    const ushortT* __restrict__ A2,   // OUTMODE0: [NM x ND] ; OUTMODE1: [NM x K2]
    const ushortT* __restrict__ Wt,   // OUTMODE0: WtH base ; OUTMODE1: WtO
    const float* __restrict__ b0, const float* __restrict__ b1, const float* __restrict__ b2,
    ushortT* __restrict__ Qo, ushortT* __restrict__ Ko, ushortT* __restrict__ Vtg,
    float* __restrict__ Ofp)
{
    const int z = blockIdx.z;
    const int AS = OUTMODE ? K2 : ND;   // row stride of A and B
    const ushortT* __restrict__ Bt = OUTMODE ? Wt : Wt + (size_t)z * ND * ND;
    const float* __restrict__ bias = (z == 0) ? b0 : (z == 1) ? b1 : b2;

    // XCD panel-group swizzle (bijective on [0,256)): panel m -> fixed L%8
    const int L = blockIdx.y * 8 + blockIdx.x;
    const int rx = L & 7, q = L >> 3;              // q in [0,32)
    const int m0 = (((q >> 3) << 3) + rx) * 128;   // 32 m-tiles
    const int n0 = (q & 7) * 128;                  // 8 n-tiles

    const int tid = threadIdx.x;
    const int lane = tid & 63, w = tid >> 6;
    const int wrow = w >> 1, wcol = w & 1;
    const int a = lane & 15, g = lane >> 4;

    __shared__ __align__(16) ushortT Abuf[3][128 * 32];   // 3 x 8 KB
    __shared__ __align__(16) ushortT Bbuf[3][128 * 32];   // 3 x 8 KB

    f32x4 acc[4][4] = {};

    // hoisted per-thread staging addresses
    const int rS  = tid >> 2;                       // 0..63
    const int scS = (tid & 3) ^ ((rS >> 1) & 3);    // src-side XOR swizzle (row-dep)
    const ushortT* pA0 = A2 + (size_t)(m0 + rS) * AS + (scS << 3);
    const ushortT* pA1 = pA0 + (size_t)64 * AS;     // rows +64: same swizzle (64>>1 ≡ 0 mod 4)
    const ushortT* pB0 = Bt + (size_t)(n0 + rS) * AS + (scS << 3);
    const ushortT* pB1 = pB0 + (size_t)64 * AS;

    const int swz = (a >> 1) & 3;
    const int nst = OUTMODE ? 48 : 32;
    const int ks0 = OUTMODE ? z * 48 : 0;

    auto stage = [&](int bufi, int ks) {
        const int kp = ks * 32;
        const int ac = (kp < ND) ? kp : kp - ND;                           // A: [hi,hi,lo]
        const int bc = OUTMODE ? ((kp < 2 * ND) ? kp : kp - 2 * ND) : kp;  // B: [hi,lo,hi]
        gl_lds16(pA0 + ac, &Abuf[bufi][(w * 64) * 8]);
        gl_lds16(pA1 + ac, &Abuf[bufi][(256 + w * 64) * 8]);
        gl_lds16(pB0 + bc, &Bbuf[bufi][(w * 64) * 8]);
        gl_lds16(pB1 + bc, &Bbuf[bufi][(256 + w * 64) * 8]);
    };

    stage(0, ks0);
    stage(1, ks0 + 1);                 // 8 loads/thread outstanding
    int cur = 0;
    for (int i = 0; i < nst; ++i) {
        if (i + 1 < nst) {
            asm volatile("s_waitcnt vmcnt(4)" ::: "memory");   // stage(i) landed
        } else {
            asm volatile("s_waitcnt vmcnt(0)" ::: "memory");
        }
        __builtin_amdgcn_s_barrier();

        if (i + 2 < nst) {
            int nb = cur + 2; if (nb >= 3) nb -= 3;
            stage(nb, ks0 + i + 2);    // overwrites buf[(i-1)%3]: safe post-barrier
        }

        bf16x8 af[4], bfr[4];
#pragma unroll
        for (int ii = 0; ii < 4; ++ii)
            af[ii] = *(const bf16x8*)&Abuf[cur][(wrow * 64 + ii * 16 + a) * 32 + ((g ^ swz) << 3)];
#pragma unroll
        for (int j = 0; j < 4; ++j)
            bfr[j] = *(const bf16x8*)&Bbuf[cur][(wcol * 64 + j * 16 + a) * 32 + ((g ^ swz) << 3)];
#pragma unroll
        for (int ii = 0; ii < 4; ++ii)
#pragma unroll
            for (int j = 0; j < 4; ++j)
                acc[ii][j] = __builtin_amdgcn_mfma_f32_16x16x32_bf16(af[ii], bfr[j], acc[ii][j], 0, 0, 0);

        ++cur; if (cur == 3) cur = 0;
    }

    float bj[4];
    if (OUTMODE == 0) {
#pragma unroll
        for (int j = 0; j < 4; ++j) bj[j] = bias[n0 + wcol * 64 + j * 16 + a];
    }

#pragma unroll
    for (int i = 0; i < 4; ++i) {
#pragma unroll
        for (int r = 0; r < 4; ++r) {
            int grow = m0 + wrow * 64 + i * 16 + g * 4 + r;
#pragma unroll
            for (int j = 0; j < 4; ++j) {
                int gcol = n0 + wcol * 64 + j * 16 + a;
                if (OUTMODE == 1) {
                    atomicAdd(&Ofp[(size_t)grow * ND + gcol], acc[i][j][r]);
                } else {
                    float v = acc[i][j][r] + bj[j];
                    int b = grow >> 11, s = grow & (NS - 1);
                    int h = gcol >> 6, dh = gcol & 63;
                    if (z == 0) {
                        Qo[((size_t)(b * NH + h) * NS + s) * NDH + dh] = f2bf(v * QSC);
                    } else if (z == 1) {
                        Ko[((size_t)(b * NH + h) * NS + s) * NDH + dh] = f2bf(v);
                    } else {
                        Vtg[((size_t)(b * NH + h) * NDH + dh) * NS + s] = f2bf(v);
                    }
                }
            }
        }
    }
}

// ---------------------------------------------------------------------------
// Flash attention, 32x32x16 MFMA, swapped QK^T, in-register P.
// pi-trick: K rows permuted into the A-operand so each lane's St registers
// hold exactly the PV B-fragment k-chunks -> zero cross-lane P exchange.
//   A row rho holds kv = s*32 + pi(rho), pi: bits (b4,b3,b2,b1b0)->(b3,b2,b4,b1b0)
//   => lane reg r (=a+4t'+8u) holds kv = s*32 + 16t' + 8*hb + 4u + a.
// Q pre-scaled by 0.125*log2e -> exp2-domain softmax; cvt_pk packing;
// defer-max (THR=8). Block = 4 waves x 32 q. KV tile 64, dbuf gl_lds.
// ---------------------------------------------------------------------------
__global__ __launch_bounds__(256) void attn_fwd2(
    const ushortT* __restrict__ Q, const ushortT* __restrict__ K,
    const ushortT* __restrict__ Vt, ushortT* __restrict__ A2o)
{
    const int bh = blockIdx.y;
    const int b = bh >> 4, h = bh & 15;
    const int q0 = blockIdx.x * 128;
    const int tid = threadIdx.x, lane = tid & 63, w = tid >> 6;
    const int ql = lane & 31;   // this lane's q (col of St / O^T)
    const int hb = lane >> 5;   // k-half selector

    // pi-permuted kv row for the QK^T A-operand read
    const int prow = (((lane >> 3) & 1) << 4) | (((lane >> 2) & 1) << 3)
                   | (((lane >> 4) & 1) << 2) | (lane & 3);
    const int psw = prow & 7;

    // 32 KB total: [K dbuf 16KB | V dbuf 16KB]; reused as epilogue scratch
    __shared__ __align__(16) unsigned smem4[8192];
    ushortT* sK = (ushortT*)smem4;          // [2][64*64]
    ushortT* sV = sK + 2 * 4096;            // [2][64*64]

    const ushortT* __restrict__ Kb  = K  + (size_t)bh * NS * NDH;   // [s][64]
    const ushortT* __restrict__ Vtb = Vt + (size_t)bh * NDH * NS;   // [d][S]

    // Q fragments (B-operand), already scaled: col=ql, k -> d = kc*16 + hb*8 + j
    bf16x8 qf[4];
    {
        const ushortT* qrow = Q + (size_t)bh * NS * NDH + (size_t)(q0 + w * 32 + ql) * NDH + hb * 8;
#pragma unroll
        for (int kc = 0; kc < 4; ++kc) qf[kc] = *(const bf16x8*)(qrow + kc * 16);
    }

    const int srw = lane >> 3;   // staging: row-in-group 0..7
    const int scc = lane & 7;    // staging: chunk 0..7

    float m_run = -INFINITY, l_run = 0.f;
    f32x16 oat[2] = {};

    // ---- stage tile 0 into buf 0 ----
#pragma unroll
    for (int c = 0; c < 2; ++c) {
        int rK = c * 32 + w * 8 + srw;
        gl_lds16(&Kb[(size_t)rK * NDH + ((scc ^ srw) << 3)], &sK[(c * 256 + w * 64) * 8]);
        gl_lds16(&Vtb[(size_t)rK * NS + ((scc ^ srw) << 3)], &sV[(c * 256 + w * 64) * 8]);
    }

    for (int t = 0; t < NS / 64; ++t) {
        const int cur = t & 1;
        __syncthreads();   // buf[cur] ready (loads are a full tile old); prev reads done
        if (t + 1 < NS / 64) {
            const int nxt = cur ^ 1;
            const int kv1 = (t + 1) * 64;
#pragma unroll
            for (int c = 0; c < 2; ++c) {
                int rK = c * 32 + w * 8 + srw;
                gl_lds16(&Kb[(size_t)(kv1 + rK) * NDH + ((scc ^ srw) << 3)],
                         &sK[(nxt * 4096) + (c * 256 + w * 64) * 8]);
                gl_lds16(&Vtb[(size_t)rK * NS + kv1 + ((scc ^ srw) << 3)],
                         &sV[(nxt * 4096) + (c * 256 + w * 64) * 8]);
            }
        }
        const ushortT* kbuf = sK + cur * 4096;
        const ushortT* vbuf = sV + cur * 4096;

        // ---- St[s] = K_pi @ Q^T (exp2-domain scores, pi-permuted rows) ----
        f32x16 st[2] = {};
#pragma unroll
        for (int s = 0; s < 2; ++s) {
            const int kv = s * 32 + prow;
#pragma unroll
            for (int kc = 0; kc < 4; ++kc) {
                bf16x8 kf = *(const bf16x8*)&kbuf[kv * 64 + (((kc * 2 + hb) ^ psw) << 3)];
                st[s] = __builtin_amdgcn_mfma_f32_32x32x16_bf16(kf, qf[kc], st[s], 0, 0, 0);
            }
        }

        // ---- online softmax; lane owns q = ql (pair with lane^32) ----
        float mx = -INFINITY;
#pragma unroll
        for (int s = 0; s < 2; ++s)
#pragma unroll
            for (int r = 0; r < 16; ++r) mx = fmaxf(mx, st[s][r]);
        mx = fmaxf(mx, __shfl_xor(mx, 32));

        if (!__all(mx - m_run <= 8.0f)) {   // defer-max: P bounded by 2^8
            float mn = fmaxf(m_run, mx);
            float al = __builtin_amdgcn_exp2f(m_run - mn);
            m_run = mn;
            l_run *= al;
#pragma unroll
            for (int dt = 0; dt < 2; ++dt)
#pragma unroll
                for (int r = 0; r < 16; ++r) oat[dt][r] *= al;
        }
        float rs = 0.f;
#pragma unroll
        for (int s = 0; s < 2; ++s)
#pragma unroll
            for (int r = 0; r < 16; ++r) {
                float e = __builtin_amdgcn_exp2f(st[s][r] - m_run);
                st[s][r] = e;
                rs += e;
            }
        rs += __shfl_xor(rs, 32);
        l_run += rs;

        // ---- O^T += V^T @ P^T : P B-frag directly from own registers ----
#pragma unroll
        for (int ts = 0; ts < 4; ++ts) {
            const int s = ts >> 1, t4 = (ts & 1) * 4;
            union { unsigned u[4]; bf16x8 v; } pf;
            pf.u[0] = cvt_pk_bf16(st[s][t4 + 0],  st[s][t4 + 1]);
            pf.u[1] = cvt_pk_bf16(st[s][t4 + 2],  st[s][t4 + 3]);
            pf.u[2] = cvt_pk_bf16(st[s][t4 + 8],  st[s][t4 + 9]);
            pf.u[3] = cvt_pk_bf16(st[s][t4 + 10], st[s][t4 + 11]);
#pragma unroll
            for (int dt = 0; dt < 2; ++dt) {
                bf16x8 vf = *(const bf16x8*)&vbuf[(dt * 32 + ql) * 64 + (((ts * 2 + hb) ^ (ql & 7)) << 3)];
                oat[dt] = __builtin_amdgcn_mfma_f32_32x32x16_bf16(vf, pf.v, oat[dt], 0, 0, 0);
            }
        }
    }

    // ---- epilogue: O^T -> LDS (xor-swizzled) -> split hi/lo gathered store ----
    __syncthreads();
    unsigned* osc = smem4 + w * 2048;   // per-wave [32 q][64 d]
    float inv = 1.0f / l_run;
#pragma unroll
    for (int dt = 0; dt < 2; ++dt)
#pragma unroll
        for (int r = 0; r < 16; ++r) {
            int d = dt * 32 + (r & 3) + 8 * (r >> 2) + 4 * hb;
            float o = oat[dt][r] * inv;
            unsigned short hbx = f2bf(o);
            unsigned short lbx = f2bf(o - bf2f(hbx));
            osc[ql * 64 + (d ^ ql)] = (unsigned)hbx | ((unsigned)lbx << 16);
        }
    __syncthreads();
    const int qrd = lane >> 3;
    const int dbase = (lane & 7) * 8;
#pragma unroll
    for (int p = 0; p < 4; ++p) {
        int qq = p * 8 + qrd;
        unsigned wv[8];
#pragma unroll
        for (int k = 0; k < 8; ++k)
            wv[k] = osc[qq * 64 + ((dbase + k) ^ qq)];
        union { ushortT s[8]; bf16x8 v; } hs, ls;
#pragma unroll
        for (int k = 0; k < 8; ++k) {
            hs.s[k] = (ushortT)(wv[k] & 0xffffu);
            ls.s[k] = (ushortT)(wv[k] >> 16);
        }
        size_t row = (size_t)(b * NS + q0 + w * 32 + qq) * K2 + h * 64 + dbase;
        *(bf16x8*)&A2o[row]      = hs.v;
        *(bf16x8*)&A2o[row + ND] = ls.v;
    }
}

// ---------------------------------------------------------------------------
extern "C" void kernel_launch(void* const* d_in, const int* in_sizes, int n_in,
                              void* d_out, int out_size, void* d_ws, size_t ws_size,
                              hipStream_t stream)
{
    const float* x  = (const float*)d_in[0];
    const float* Wq = (const float*)d_in[1];
    const float* bq = (const float*)d_in[2];
    const float* Wk = (const float*)d_in[3];
    const float* bk = (const float*)d_in[4];
    const float* Wv = (const float*)d_in[5];
    const float* bv = (const float*)d_in[6];
    const float* Wo = (const float*)d_in[7];
    const float* bo = (const float*)d_in[8];
    float* out = (float*)d_out;

    // ws: xh 8.4 | WtH 6.3 | WtO 4.2 | Q 8.4 | K 8.4 | Vt 8.4 | A2 16.8 = 60.8 MB
    ushortT* xh  = (ushortT*)d_ws;
    ushortT* WtH = xh  + (size_t)NM * ND;
    ushortT* WtO = WtH + (size_t)3 * ND * ND;
    ushortT* Qb  = WtO + (size_t)ND * K2;
    ushortT* Kb  = Qb  + (size_t)NM * ND;
    ushortT* Vtg = Kb  + (size_t)NM * ND;
    ushortT* A2  = Vtg + (size_t)NM * ND;

    split_x<<<dim3(NM * ND / 1024), 256, 0, stream>>>(x, xh);
    split_w_t<<<dim3(16, 16, 4), 256, 0, stream>>>(Wq, Wk, Wv, Wo, WtH, WtO);
    gemm_split<0><<<dim3(8, 32, 3), 256, 0, stream>>>(
        xh, WtH, bq, bk, bv, Qb, Kb, Vtg, nullptr);
    attn_fwd2<<<dim3(NS / 128, NB * NH), 256, 0, stream>>>(Qb, Kb, Vtg, A2);
    out_init<<<dim3(NM * ND / 1024), 256, 0, stream>>>(bo, out);
    gemm_split<1><<<dim3(8, 32, 2), 256, 0, stream>>>(
        A2, WtO, bo, bo, bo, nullptr, nullptr, nullptr, out);
}